// Round 1
// baseline (1216.535 us; speedup 1.0000x reference)
//
#include <hip/hip_runtime.h>
#include <hip/hip_bf16.h>
#include <stdint.h>

#define D_MODEL 1024
#define TOKENS  2048
#define HEADS   16
#define HDIM    64
#define NQKV    3072      // 3*D_MODEL
#define MROWS   4096      // BATCH*TOKENS

typedef __attribute__((ext_vector_type(4))) float f32x4;
typedef __attribute__((ext_vector_type(8))) short bf16x8;

__device__ __forceinline__ unsigned short f2bf(float f) {
  union { float f; unsigned u; } v; v.f = f;
  unsigned u = v.u + 0x7FFFu + ((v.u >> 16) & 1u);   // RNE
  return (unsigned short)(u >> 16);
}
__device__ __forceinline__ float bf2f(unsigned short b) {
  union { unsigned u; float f; } v; v.u = ((unsigned)b) << 16;
  return v.f;
}

// ---------------------------------------------------------------------------
// QKV GEMM: QKV[m][f] = sum_c X[m][c] * W[f][c]   (m=4096, f=3072, c=1024)
// 128x128 tile, BK=32, 4 waves, each wave 64x64 via 4x4 mfma_f32_16x16x32_bf16.
// fp32 inputs converted to bf16 during LDS staging. Output bf16 into ws.
// ---------------------------------------------------------------------------
__global__ __launch_bounds__(256) void qkv_gemm(const float* __restrict__ X,
                                                const float* __restrict__ W,
                                                unsigned short* __restrict__ QKV) {
  __shared__ unsigned short sA[128 * 32];
  __shared__ unsigned short sB[128 * 32];
  const int tid  = threadIdx.x;
  const int lane = tid & 63;
  const int wave = tid >> 6;
  const int wr = wave >> 1, wc = wave & 1;
  const int row0 = blockIdx.x * 128;   // M tile
  const int col0 = blockIdx.y * 128;   // N tile

  f32x4 acc[4][4];
#pragma unroll
  for (int i = 0; i < 4; ++i)
#pragma unroll
    for (int j = 0; j < 4; ++j)
#pragma unroll
      for (int r = 0; r < 4; ++r) acc[i][j][r] = 0.f;

  const int srow = tid >> 1;        // 0..127
  const int scol = (tid & 1) * 16;  // 0 or 16

  union U16 { unsigned short s[8]; uint4 v; };

#pragma unroll 1
  for (int k0 = 0; k0 < D_MODEL; k0 += 32) {
    // ---- stage A (X tile) and B (W tile) as bf16 ----
    {
      const float* ga = X + (size_t)(row0 + srow) * D_MODEL + k0 + scol;
      const float* gb = W + (size_t)(col0 + srow) * D_MODEL + k0 + scol;
      float va[16], vb[16];
#pragma unroll
      for (int i = 0; i < 4; ++i) {
        float4 t = ((const float4*)ga)[i];
        va[4*i+0] = t.x; va[4*i+1] = t.y; va[4*i+2] = t.z; va[4*i+3] = t.w;
        float4 u = ((const float4*)gb)[i];
        vb[4*i+0] = u.x; vb[4*i+1] = u.y; vb[4*i+2] = u.z; vb[4*i+3] = u.w;
      }
      U16 ua0, ua1, ub0, ub1;
#pragma unroll
      for (int e = 0; e < 8; ++e) {
        ua0.s[e] = f2bf(va[e]);   ua1.s[e] = f2bf(va[8 + e]);
        ub0.s[e] = f2bf(vb[e]);   ub1.s[e] = f2bf(vb[8 + e]);
      }
      *(uint4*)&sA[srow * 32 + scol + 0] = ua0.v;
      *(uint4*)&sA[srow * 32 + scol + 8] = ua1.v;
      *(uint4*)&sB[srow * 32 + scol + 0] = ub0.v;
      *(uint4*)&sB[srow * 32 + scol + 8] = ub1.v;
    }
    __syncthreads();

    // ---- fragments + MFMA ----
    const int lrow = lane & 15;
    const int lk   = (lane >> 4) * 8;
    bf16x8 av[4], bv[4];
#pragma unroll
    for (int i = 0; i < 4; ++i)
      av[i] = *(const bf16x8*)&sA[(wr * 64 + i * 16 + lrow) * 32 + lk];
#pragma unroll
    for (int j = 0; j < 4; ++j)
      bv[j] = *(const bf16x8*)&sB[(wc * 64 + j * 16 + lrow) * 32 + lk];
#pragma unroll
    for (int i = 0; i < 4; ++i)
#pragma unroll
      for (int j = 0; j < 4; ++j)
        acc[i][j] = __builtin_amdgcn_mfma_f32_16x16x32_bf16(av[i], bv[j], acc[i][j], 0, 0, 0);
    __syncthreads();
  }

  // ---- epilogue: D[row=(l>>4)*4+r][col=l&15] (guide-verified layout) ----
  const int orow = row0 + wr * 64 + (lane >> 4) * 4;
  const int ocol = col0 + wc * 64 + (lane & 15);
#pragma unroll
  for (int i = 0; i < 4; ++i)
#pragma unroll
    for (int j = 0; j < 4; ++j)
#pragma unroll
      for (int r = 0; r < 4; ++r)
        QKV[(size_t)(orow + i * 16 + r) * NQKV + ocol + j * 16] = f2bf(acc[i][j][r]);
}

// ---------------------------------------------------------------------------
// Causal flash attention (vector VALU version, round-0 baseline).
// Block = 4 waves, 64 queries (lane owns one query row entirely).
// The 4 waves split the key range (strided 32-key chunks) and merge partials
// through LDS at the end (flash-decoding style) to balance the causal tail.
// ---------------------------------------------------------------------------
__global__ __launch_bounds__(256) void attn(const unsigned short* __restrict__ QKV,
                                            float* __restrict__ Out) {
  __shared__ float smem[16384];   // 64KB; per-wave: K[2048] V[2048] @ wave*4096
  const int tid  = threadIdx.x;
  const int lane = tid & 63;
  const int wave = tid >> 6;
  const int q0 = blockIdx.x * 64;
  const int bh = blockIdx.y;
  const int b = bh >> 4, h = bh & 15;
  const int q = q0 + lane;

  float* sKw = smem + wave * 4096;
  float* sVw = sKw + 2048;

  // load + pre-scale Q row (64 bf16 -> f32)
  const unsigned short* qrow = QKV + (size_t)(b * TOKENS + q) * NQKV + h * HDIM;
  float qreg[64];
#pragma unroll
  for (int i = 0; i < 16; ++i) {
    ushort4 u = ((const ushort4*)qrow)[i];
    qreg[4*i+0] = bf2f(u.x) * 0.125f;
    qreg[4*i+1] = bf2f(u.y) * 0.125f;
    qreg[4*i+2] = bf2f(u.z) * 0.125f;
    qreg[4*i+3] = bf2f(u.w) * 0.125f;
  }

  float m = -1e30f, l = 0.f;
  float accv[64];
#pragma unroll
  for (int d = 0; d < 64; ++d) accv[d] = 0.f;

  const unsigned short* Kbase = QKV + (size_t)(b * TOKENS) * NQKV + D_MODEL + h * HDIM;
  const unsigned short* Vbase = Kbase + D_MODEL;

  const int nch = (q0 >> 5) + 2;    // 32-key chunks covering keys 0..q0+63
  const int lr  = lane >> 4;        // 0..3
  const int lc  = (lane & 15) * 4;  // 0..60

  for (int c = wave; c < nch; c += 4) {
    // stage 32 keys x 64 dims of K and V into this wave's LDS region (f32)
#pragma unroll
    for (int it = 0; it < 8; ++it) {
      int rr = it * 4 + lr;                       // 0..31
      size_t grow = (size_t)(c * 32 + rr) * NQKV;
      ushort4 ku = *(const ushort4*)(Kbase + grow + lc);
      ushort4 vu = *(const ushort4*)(Vbase + grow + lc);
      float4 kf; kf.x = bf2f(ku.x); kf.y = bf2f(ku.y); kf.z = bf2f(ku.z); kf.w = bf2f(ku.w);
      float4 vf; vf.x = bf2f(vu.x); vf.y = bf2f(vu.y); vf.z = bf2f(vu.z); vf.w = bf2f(vu.w);
      *(float4*)&sKw[rr * 64 + lc] = kf;
      *(float4*)&sVw[rr * 64 + lc] = vf;
    }
    // same-wave DS ordering: LDS requests of a wave are processed in order.

#pragma unroll 2
    for (int r = 0; r < 32; ++r) {
      const int kg = c * 32 + r;
      float s0 = 0.f, s1 = 0.f, s2 = 0.f, s3 = 0.f;
#pragma unroll
      for (int dc = 0; dc < 16; ++dc) {
        float4 kk = *(const float4*)&sKw[r * 64 + dc * 4];
        s0 = fmaf(qreg[4*dc+0], kk.x, s0);
        s1 = fmaf(qreg[4*dc+1], kk.y, s1);
        s2 = fmaf(qreg[4*dc+2], kk.z, s2);
        s3 = fmaf(qreg[4*dc+3], kk.w, s3);
      }
      float s = (s0 + s1) + (s2 + s3);
      const bool valid = (kg <= q);
      float sm   = valid ? s : -1e30f;
      float mnew = fmaxf(m, sm);
      float scale = __expf(m - mnew);
      float p     = valid ? __expf(s - mnew) : 0.f;
      l = l * scale + p;
#pragma unroll
      for (int dc = 0; dc < 16; ++dc) {
        float4 vv = *(const float4*)&sVw[r * 64 + dc * 4];
        accv[4*dc+0] = fmaf(accv[4*dc+0], scale, p * vv.x);
        accv[4*dc+1] = fmaf(accv[4*dc+1], scale, p * vv.y);
        accv[4*dc+2] = fmaf(accv[4*dc+2], scale, p * vv.z);
        accv[4*dc+3] = fmaf(accv[4*dc+3], scale, p * vv.w);
      }
      m = mnew;
    }
  }

  // ---- merge the 4 per-wave partials (reuse LDS; all staging use is done) ----
  __syncthreads();
  if (wave != 0) {
    float* P = smem + ((wave - 1) * 64 + lane) * 66;
    P[0] = m; P[1] = l;
#pragma unroll
    for (int d = 0; d < 64; ++d) P[2 + d] = accv[d];
  }
  __syncthreads();
  if (wave == 0) {
#pragma unroll 1
    for (int w = 1; w < 4; ++w) {
      const float* P = smem + ((w - 1) * 64 + lane) * 66;
      float mw = P[0], lw = P[1];
      float M  = fmaxf(m, mw);
      float sc = __expf(m - M), sw = __expf(mw - M);
      l = l * sc + lw * sw;
#pragma unroll
      for (int d = 0; d < 64; ++d) accv[d] = accv[d] * sc + P[2 + d] * sw;
      m = M;
    }
    float inv = 1.f / l;
    float* orow = Out + (size_t)(b * TOKENS + q) * D_MODEL + h * HDIM;
#pragma unroll
    for (int dc = 0; dc < 16; ++dc) {
      float4 o;
      o.x = accv[4*dc+0] * inv; o.y = accv[4*dc+1] * inv;
      o.z = accv[4*dc+2] * inv; o.w = accv[4*dc+3] * inv;
      ((float4*)orow)[dc] = o;
    }
  }
}

extern "C" void kernel_launch(void* const* d_in, const int* in_sizes, int n_in,
                              void* d_out, int out_size, void* d_ws, size_t ws_size,
                              hipStream_t stream) {
  const float* X = (const float*)d_in[0];    // [2,2048,1024]
  const float* W = (const float*)d_in[1];    // [3072,1024]
  float* Out = (float*)d_out;                // [2,2048,1024]
  unsigned short* QKV = (unsigned short*)d_ws;  // [4096][3072] bf16 (25.2 MB)

  dim3 g1(MROWS / 128, NQKV / 128), b1(256);
  qkv_gemm<<<g1, b1, 0, stream>>>(X, W, QKV);

  dim3 g2(TOKENS / 64, 2 * HEADS), b2(256);
  attn<<<g2, b2, 0, stream>>>(QKV, Out);
}

// Round 3
// 239.185 us; speedup vs baseline: 5.0862x; 5.0862x over previous
//
#include <hip/hip_runtime.h>
#include <hip/hip_bf16.h>
#include <stdint.h>

#define D_MODEL 1024
#define TOKENS  2048
#define HEADS   16
#define HDIM    64
#define NQKV    3072      // 3*D_MODEL
#define MROWS   4096      // BATCH*TOKENS

typedef __attribute__((ext_vector_type(4))) float f32x4;
typedef __attribute__((ext_vector_type(8))) short bf16x8;

__device__ __forceinline__ unsigned short f2bf(float f) {
  union { float f; unsigned u; } v; v.f = f;
  unsigned u = v.u + 0x7FFFu + ((v.u >> 16) & 1u);   // RNE
  return (unsigned short)(u >> 16);
}
__device__ __forceinline__ float bf2f(unsigned short b) {
  union { unsigned u; float f; } v; v.u = ((unsigned)b) << 16;
  return v.f;
}

// ---------------------------------------------------------------------------
// QKV GEMM: QKV[m][f] = sum_c X[m][c] * W[f][c]   (unchanged, verified round 1)
// ---------------------------------------------------------------------------
__global__ __launch_bounds__(256) void qkv_gemm(const float* __restrict__ X,
                                                const float* __restrict__ W,
                                                unsigned short* __restrict__ QKV) {
  __shared__ unsigned short sA[128 * 32];
  __shared__ unsigned short sB[128 * 32];
  const int tid  = threadIdx.x;
  const int lane = tid & 63;
  const int wave = tid >> 6;
  const int wr = wave >> 1, wc = wave & 1;
  const int row0 = blockIdx.x * 128;
  const int col0 = blockIdx.y * 128;

  f32x4 acc[4][4];
#pragma unroll
  for (int i = 0; i < 4; ++i)
#pragma unroll
    for (int j = 0; j < 4; ++j)
#pragma unroll
      for (int r = 0; r < 4; ++r) acc[i][j][r] = 0.f;

  const int srow = tid >> 1;
  const int scol = (tid & 1) * 16;

  union U16 { unsigned short s[8]; uint4 v; };

#pragma unroll 1
  for (int k0 = 0; k0 < D_MODEL; k0 += 32) {
    {
      const float* ga = X + (size_t)(row0 + srow) * D_MODEL + k0 + scol;
      const float* gb = W + (size_t)(col0 + srow) * D_MODEL + k0 + scol;
      float va[16], vb[16];
#pragma unroll
      for (int i = 0; i < 4; ++i) {
        float4 t = ((const float4*)ga)[i];
        va[4*i+0] = t.x; va[4*i+1] = t.y; va[4*i+2] = t.z; va[4*i+3] = t.w;
        float4 u = ((const float4*)gb)[i];
        vb[4*i+0] = u.x; vb[4*i+1] = u.y; vb[4*i+2] = u.z; vb[4*i+3] = u.w;
      }
      U16 ua0, ua1, ub0, ub1;
#pragma unroll
      for (int e = 0; e < 8; ++e) {
        ua0.s[e] = f2bf(va[e]);   ua1.s[e] = f2bf(va[8 + e]);
        ub0.s[e] = f2bf(vb[e]);   ub1.s[e] = f2bf(vb[8 + e]);
      }
      *(uint4*)&sA[srow * 32 + scol + 0] = ua0.v;
      *(uint4*)&sA[srow * 32 + scol + 8] = ua1.v;
      *(uint4*)&sB[srow * 32 + scol + 0] = ub0.v;
      *(uint4*)&sB[srow * 32 + scol + 8] = ub1.v;
    }
    __syncthreads();

    const int lrow = lane & 15;
    const int lk   = (lane >> 4) * 8;
    bf16x8 av[4], bv[4];
#pragma unroll
    for (int i = 0; i < 4; ++i)
      av[i] = *(const bf16x8*)&sA[(wr * 64 + i * 16 + lrow) * 32 + lk];
#pragma unroll
    for (int j = 0; j < 4; ++j)
      bv[j] = *(const bf16x8*)&sB[(wc * 64 + j * 16 + lrow) * 32 + lk];
#pragma unroll
    for (int i = 0; i < 4; ++i)
#pragma unroll
      for (int j = 0; j < 4; ++j)
        acc[i][j] = __builtin_amdgcn_mfma_f32_16x16x32_bf16(av[i], bv[j], acc[i][j], 0, 0, 0);
    __syncthreads();
  }

  const int orow = row0 + wr * 64 + (lane >> 4) * 4;
  const int ocol = col0 + wc * 64 + (lane & 15);
#pragma unroll
  for (int i = 0; i < 4; ++i)
#pragma unroll
    for (int j = 0; j < 4; ++j)
#pragma unroll
      for (int r = 0; r < 4; ++r)
        QKV[(size_t)(orow + i * 16 + r) * NQKV + ocol + j * 16] = f2bf(acc[i][j][r]);
}

// ---------------------------------------------------------------------------
// MFMA causal flash attention.
// 4 waves, QBLK=64 (16 q-rows/wave), KVBLK=64.
// K in LDS row-major [key][dim] bf16, XOR-swizzled (^((row&7)<<4) on byte addr).
// V in LDS transposed [dim][key] bf16, same swizzle (reg 4x4 block transpose).
// P (probabilities) round-trip through per-wave LDS tile, same swizzle.
// Softmax wave-parallel: each q-row lives across a 16-lane group; reductions
// via __shfl_xor 1/2/4/8. exp2-domain (Q pre-scaled by 0.125*log2e).
// ---------------------------------------------------------------------------
__global__ __launch_bounds__(256) void attn_mfma(const unsigned short* __restrict__ QKV,
                                                 float* __restrict__ Out) {
  __shared__ unsigned short sK [64 * 64];   // 8 KB
  __shared__ unsigned short sVt[64 * 64];   // 8 KB
  __shared__ unsigned short sP [4 * 16 * 64]; // 8 KB, per-wave 16x64

  const int tid  = threadIdx.x;
  const int lane = tid & 63;
  const int wave = tid >> 6;
  const int qt = blockIdx.x;            // q-tile 0..31
  const int bh = blockIdx.y;
  const int b = bh >> 4, h = bh & 15;
  const int q0 = qt * 64;

  const unsigned short* Qbase = QKV + (size_t)(b * TOKENS) * NQKV + h * HDIM;
  const unsigned short* Kbase = Qbase + D_MODEL;
  const unsigned short* Vbase = Kbase + D_MODEL;

  const int l15 = lane & 15;
  const int lg  = lane >> 4;            // 16-lane group id 0..3

  // ---- Q fragments in registers, pre-scaled by 0.125*log2(e) ----
  bf16x8 qf[2];
  {
    const int qrow = q0 + wave * 16 + l15;
    union { unsigned short s[8]; bf16x8 v; ushort4 u[2]; } tmp;
#pragma unroll
    for (int c = 0; c < 2; ++c) {
      const unsigned short* p = Qbase + (size_t)qrow * NQKV + c * 32 + lg * 8;
      tmp.u[0] = ((const ushort4*)p)[0];
      tmp.u[1] = ((const ushort4*)p)[1];
#pragma unroll
      for (int e = 0; e < 8; ++e)
        tmp.s[e] = f2bf(bf2f(tmp.s[e]) * 0.18033688011112042f);
      qf[c] = tmp.v;
    }
  }

  f32x4 o[4];                 // O frags: dim-block db, col=l15, row=lg*4+r
#pragma unroll
  for (int db = 0; db < 4; ++db)
#pragma unroll
    for (int r = 0; r < 4; ++r) o[db][r] = 0.f;
  float m[4], l[4];
#pragma unroll
  for (int r = 0; r < 4; ++r) { m[r] = -1e30f; l[r] = 0.f; }

  // staging thread mappings
  const int skey = tid >> 2;            // K: key row 0..63
  const int sd0  = (tid & 3) * 16;      // K: dim start
  const int vk0  = (tid & 15) * 4;      // V: key start
  const int vd0  = (tid >> 4) * 4;      // V: dim start

  char* const cK  = (char*)sK;
  char* const cVt = (char*)sVt;
  char* const cP  = (char*)(sP + wave * 1024);   // this wave's 16x64 tile

  const int nkt = qt + 1;
#pragma unroll 1
  for (int kt = 0; kt < nkt; ++kt) {
    const int kbase = kt * 64;

    // ---- stage K (row-major, swizzled) ----
    {
      const unsigned short* src = Kbase + (size_t)(kbase + skey) * NQKV + sd0;
      uint4 a0 = ((const uint4*)src)[0];
      uint4 a1 = ((const uint4*)src)[1];
      const int off = skey * 128 + sd0 * 2;
      const int sw  = (skey & 7) << 4;
      *(uint4*)(cK + ((off     ) ^ sw)) = a0;
      *(uint4*)(cK + ((off + 16) ^ sw)) = a1;
    }
    // ---- stage V transposed (reg 4x4 block transpose, swizzled) ----
    {
      const unsigned short* vs = Vbase + (size_t)(kbase + vk0) * NQKV + vd0;
      ushort4 r0 = *(const ushort4*)(vs);
      ushort4 r1 = *(const ushort4*)(vs + NQKV);
      ushort4 r2 = *(const ushort4*)(vs + 2 * NQKV);
      ushort4 r3 = *(const ushort4*)(vs + 3 * NQKV);
      ushort4 c0, c1, c2, c3;
      c0.x = r0.x; c0.y = r1.x; c0.z = r2.x; c0.w = r3.x;
      c1.x = r0.y; c1.y = r1.y; c1.z = r2.y; c1.w = r3.y;
      c2.x = r0.z; c2.y = r1.z; c2.z = r2.z; c2.w = r3.z;
      c3.x = r0.w; c3.y = r1.w; c3.z = r2.w; c3.w = r3.w;
#pragma unroll
      for (int e = 0; e < 4; ++e) {
        const int dim = vd0 + e;
        const int off = (dim * 128 + vk0 * 2) ^ ((dim & 7) << 4);
        ushort4 cc = (e == 0) ? c0 : (e == 1) ? c1 : (e == 2) ? c2 : c3;
        *(ushort4*)(cVt + off) = cc;
      }
    }
    __syncthreads();

    // ---- QK^T: S[16q][64key] per wave ----
    f32x4 s[4];
#pragma unroll
    for (int f = 0; f < 4; ++f)
#pragma unroll
      for (int r = 0; r < 4; ++r) s[f][r] = 0.f;
#pragma unroll
    for (int c = 0; c < 2; ++c) {
#pragma unroll
      for (int f = 0; f < 4; ++f) {
        const int key = f * 16 + l15;
        const int off = (key * 128 + (c * 32 + lg * 8) * 2) ^ ((key & 7) << 4);
        bf16x8 kf = *(const bf16x8*)(cK + off);
        s[f] = __builtin_amdgcn_mfma_f32_16x16x32_bf16(qf[c], kf, s[f], 0, 0, 0);
      }
    }

    // ---- causal mask + online softmax (exp2 domain) ----
    const int qg = q0 + wave * 16 + lg * 4;   // + r = this lane's q rows
#pragma unroll
    for (int f = 0; f < 4; ++f) {
      const int kg = kbase + f * 16 + l15;
#pragma unroll
      for (int r = 0; r < 4; ++r)
        if (kg > qg + r) s[f][r] = -1e30f;
    }
    float pv[4][4];
#pragma unroll
    for (int r = 0; r < 4; ++r) {
      float mx = fmaxf(fmaxf(s[0][r], s[1][r]), fmaxf(s[2][r], s[3][r]));
      mx = fmaxf(mx, __shfl_xor(mx, 1));
      mx = fmaxf(mx, __shfl_xor(mx, 2));
      mx = fmaxf(mx, __shfl_xor(mx, 4));
      mx = fmaxf(mx, __shfl_xor(mx, 8));
      const float mnew = fmaxf(m[r], mx);
      const float corr = exp2f(m[r] - mnew);
      m[r] = mnew;
      float ps = 0.f;
#pragma unroll
      for (int f = 0; f < 4; ++f) {
        const float p = exp2f(s[f][r] - mnew);
        pv[f][r] = p;
        ps += p;
      }
      ps += __shfl_xor(ps, 1);
      ps += __shfl_xor(ps, 2);
      ps += __shfl_xor(ps, 4);
      ps += __shfl_xor(ps, 8);
      l[r] = l[r] * corr + ps;
#pragma unroll
      for (int db = 0; db < 4; ++db) o[db][r] *= corr;
    }

    // ---- P -> LDS (bf16, row-major [q][key], swizzled) ----
#pragma unroll
    for (int f = 0; f < 4; ++f) {
      const int key = f * 16 + l15;
#pragma unroll
      for (int r = 0; r < 4; ++r) {
        const int qr = lg * 4 + r;
        *(unsigned short*)(cP + ((qr * 128 + key * 2) ^ ((qr & 7) << 4))) = f2bf(pv[f][r]);
      }
    }

    // ---- PV: O += P * V ----
#pragma unroll
    for (int c = 0; c < 2; ++c) {
      const int aoff = (l15 * 128 + (c * 32 + lg * 8) * 2) ^ ((l15 & 7) << 4);
      bf16x8 pa = *(const bf16x8*)(cP + aoff);
#pragma unroll
      for (int db = 0; db < 4; ++db) {
        const int dim = db * 16 + l15;
        const int boff = (dim * 128 + (c * 32 + lg * 8) * 2) ^ ((dim & 7) << 4);
        bf16x8 vb = *(const bf16x8*)(cVt + boff);
        o[db] = __builtin_amdgcn_mfma_f32_16x16x32_bf16(pa, vb, o[db], 0, 0, 0);
      }
    }
    __syncthreads();
  }

  // ---- epilogue ----
  float inv[4];
#pragma unroll
  for (int r = 0; r < 4; ++r) inv[r] = 1.f / l[r];
#pragma unroll
  for (int r = 0; r < 4; ++r) {
    const int q = q0 + wave * 16 + lg * 4 + r;
    float* orow = Out + (size_t)(b * TOKENS + q) * D_MODEL + h * HDIM;
#pragma unroll
    for (int db = 0; db < 4; ++db)
      orow[db * 16 + l15] = o[db][r] * inv[r];
  }
}

extern "C" void kernel_launch(void* const* d_in, const int* in_sizes, int n_in,
                              void* d_out, int out_size, void* d_ws, size_t ws_size,
                              hipStream_t stream) {
  const float* X = (const float*)d_in[0];
  const float* W = (const float*)d_in[1];
  float* Out = (float*)d_out;
  unsigned short* QKV = (unsigned short*)d_ws;   // [4096][3072] bf16

  dim3 g1(MROWS / 128, NQKV / 128), b1(256);
  qkv_gemm<<<g1, b1, 0, stream>>>(X, W, QKV);

  dim3 g2(TOKENS / 64, 2 * HEADS), b2(256);
  attn_mfma<<<g2, b2, 0, stream>>>(QKV, Out);
}

// Round 4
// 128.219 us; speedup vs baseline: 9.4880x; 1.8654x over previous
//
#include <hip/hip_runtime.h>
#include <hip/hip_bf16.h>
#include <stdint.h>

#define D_MODEL 1024
#define TOKENS  2048
#define HEADS   16
#define HDIM    64
#define NQKV    3072      // 3*D_MODEL
#define MROWS   4096      // BATCH*TOKENS

typedef __attribute__((ext_vector_type(4))) float f32x4;
typedef __attribute__((ext_vector_type(8))) short bf16x8;

__device__ __forceinline__ unsigned short f2bf(float f) {
  union { float f; unsigned u; } v; v.f = f;
  unsigned u = v.u + 0x7FFFu + ((v.u >> 16) & 1u);   // RNE
  return (unsigned short)(u >> 16);
}
__device__ __forceinline__ float bf2f(unsigned short b) {
  union { unsigned u; float f; } v; v.u = ((unsigned)b) << 16;
  return v.f;
}
__device__ __forceinline__ unsigned cvt_pk_bf16(float lo, float hi) {
  unsigned r;
  asm("v_cvt_pk_bf16_f32 %0, %1, %2" : "=v"(r) : "v"(lo), "v"(hi));
  return r;
}

#define GLOAD16(g, l)                                                          \
  __builtin_amdgcn_global_load_lds(                                            \
      (const __attribute__((address_space(1))) unsigned int*)(g),              \
      (__attribute__((address_space(3))) unsigned int*)(l), 16, 0, 0)

// ---------------------------------------------------------------------------
// fp32 -> bf16 convert pass (X then W, contiguous).  7.3M elems, 8/thread.
// ---------------------------------------------------------------------------
__global__ __launch_bounds__(256) void cvt_bf16(const float* __restrict__ X,
                                                const float* __restrict__ W,
                                                unsigned short* __restrict__ Xb,
                                                unsigned short* __restrict__ Wb) {
  const size_t NX = (size_t)MROWS * D_MODEL;        // 4194304
  size_t i = ((size_t)blockIdx.x * 256 + threadIdx.x) * 8;
  const float* src; unsigned short* dst; size_t off;
  if (i < NX) { src = X; dst = Xb; off = i; }
  else        { src = W; dst = Wb; off = i - NX; }
  float4 a = ((const float4*)(src + off))[0];
  float4 b = ((const float4*)(src + off))[1];
  union { unsigned short s[8]; uint4 v; } u;
  u.s[0] = f2bf(a.x); u.s[1] = f2bf(a.y); u.s[2] = f2bf(a.z); u.s[3] = f2bf(a.w);
  u.s[4] = f2bf(b.x); u.s[5] = f2bf(b.y); u.s[6] = f2bf(b.z); u.s[7] = f2bf(b.w);
  *(uint4*)(dst + off) = u.v;
}

// ---------------------------------------------------------------------------
// bf16 GEMM (m97 structure): 128x128 tile, BK=64, global_load_lds width=16.
// QKV[m][f] = sum_c Xb[m][c] * Wb[f][c]
// ---------------------------------------------------------------------------
__global__ __launch_bounds__(256) void gemm_bf16(const unsigned short* __restrict__ A,
                                                 const unsigned short* __restrict__ B,
                                                 unsigned short* __restrict__ C) {
  __shared__ unsigned short sA[128 * 64];   // 16 KB
  __shared__ unsigned short sB[128 * 64];   // 16 KB
  const int tid  = threadIdx.x;
  const int lane = tid & 63;
  const int wave = tid >> 6;
  const int wr = wave >> 1, wc = wave & 1;
  const int row0 = blockIdx.x * 128;
  const int col0 = blockIdx.y * 128;

  f32x4 acc[4][4];
#pragma unroll
  for (int i = 0; i < 4; ++i)
#pragma unroll
    for (int j = 0; j < 4; ++j)
#pragma unroll
      for (int r = 0; r < 4; ++r) acc[i][j][r] = 0.f;

  const int lrow = lane & 15;
  const int lg   = lane >> 4;
  // staging: wave w covers rows w*32..w*32+31; lane covers (row = +i*8+l>>3, col16B = l&7)
  const int strow = (lane >> 3);
  const int stcol = (lane & 7) * 8;       // elements

#pragma unroll 1
  for (int k0 = 0; k0 < D_MODEL; k0 += 64) {
#pragma unroll
    for (int i = 0; i < 4; ++i) {
      const int r = wave * 32 + i * 8 + strow;
      GLOAD16(A + (size_t)(row0 + r) * D_MODEL + k0 + stcol, &sA[r * 64 + stcol]);
      GLOAD16(B + (size_t)(col0 + r) * D_MODEL + k0 + stcol, &sB[r * 64 + stcol]);
    }
    __syncthreads();

    bf16x8 av[4][2], bv[4][2];
#pragma unroll
    for (int c = 0; c < 2; ++c) {
#pragma unroll
      for (int i = 0; i < 4; ++i)
        av[i][c] = *(const bf16x8*)&sA[(wr * 64 + i * 16 + lrow) * 64 + c * 32 + lg * 8];
#pragma unroll
      for (int j = 0; j < 4; ++j)
        bv[j][c] = *(const bf16x8*)&sB[(wc * 64 + j * 16 + lrow) * 64 + c * 32 + lg * 8];
    }
#pragma unroll
    for (int c = 0; c < 2; ++c)
#pragma unroll
      for (int i = 0; i < 4; ++i)
#pragma unroll
        for (int j = 0; j < 4; ++j)
          acc[i][j] = __builtin_amdgcn_mfma_f32_16x16x32_bf16(av[i][c], bv[j][c], acc[i][j], 0, 0, 0);
    __syncthreads();
  }

  const int orow = row0 + wr * 64 + (lane >> 4) * 4;
  const int ocol = col0 + wc * 64 + (lane & 15);
#pragma unroll
  for (int i = 0; i < 4; ++i)
#pragma unroll
    for (int j = 0; j < 4; ++j)
#pragma unroll
      for (int r = 0; r < 4; ++r)
        C[(size_t)(orow + i * 16 + r) * NQKV + ocol + j * 16] = f2bf(acc[i][j][r]);
}

// ---------------------------------------------------------------------------
// Fallback fp32-input GEMM (round-1 verified) for small ws.
// ---------------------------------------------------------------------------
__global__ __launch_bounds__(256) void qkv_gemm(const float* __restrict__ X,
                                                const float* __restrict__ W,
                                                unsigned short* __restrict__ QKV) {
  __shared__ unsigned short sA[128 * 32];
  __shared__ unsigned short sB[128 * 32];
  const int tid  = threadIdx.x;
  const int lane = tid & 63;
  const int wave = tid >> 6;
  const int wr = wave >> 1, wc = wave & 1;
  const int row0 = blockIdx.x * 128;
  const int col0 = blockIdx.y * 128;

  f32x4 acc[4][4];
#pragma unroll
  for (int i = 0; i < 4; ++i)
#pragma unroll
    for (int j = 0; j < 4; ++j)
#pragma unroll
      for (int r = 0; r < 4; ++r) acc[i][j][r] = 0.f;

  const int srow = tid >> 1;
  const int scol = (tid & 1) * 16;
  union U16 { unsigned short s[8]; uint4 v; };

#pragma unroll 1
  for (int k0 = 0; k0 < D_MODEL; k0 += 32) {
    {
      const float* ga = X + (size_t)(row0 + srow) * D_MODEL + k0 + scol;
      const float* gb = W + (size_t)(col0 + srow) * D_MODEL + k0 + scol;
      float va[16], vb[16];
#pragma unroll
      for (int i = 0; i < 4; ++i) {
        float4 t = ((const float4*)ga)[i];
        va[4*i+0] = t.x; va[4*i+1] = t.y; va[4*i+2] = t.z; va[4*i+3] = t.w;
        float4 u = ((const float4*)gb)[i];
        vb[4*i+0] = u.x; vb[4*i+1] = u.y; vb[4*i+2] = u.z; vb[4*i+3] = u.w;
      }
      U16 ua0, ua1, ub0, ub1;
#pragma unroll
      for (int e = 0; e < 8; ++e) {
        ua0.s[e] = f2bf(va[e]);   ua1.s[e] = f2bf(va[8 + e]);
        ub0.s[e] = f2bf(vb[e]);   ub1.s[e] = f2bf(vb[8 + e]);
      }
      *(uint4*)&sA[srow * 32 + scol + 0] = ua0.v;
      *(uint4*)&sA[srow * 32 + scol + 8] = ua1.v;
      *(uint4*)&sB[srow * 32 + scol + 0] = ub0.v;
      *(uint4*)&sB[srow * 32 + scol + 8] = ub1.v;
    }
    __syncthreads();

    const int lrow = lane & 15;
    const int lk   = (lane >> 4) * 8;
    bf16x8 av[4], bv[4];
#pragma unroll
    for (int i = 0; i < 4; ++i)
      av[i] = *(const bf16x8*)&sA[(wr * 64 + i * 16 + lrow) * 32 + lk];
#pragma unroll
    for (int j = 0; j < 4; ++j)
      bv[j] = *(const bf16x8*)&sB[(wc * 64 + j * 16 + lrow) * 32 + lk];
#pragma unroll
    for (int i = 0; i < 4; ++i)
#pragma unroll
      for (int j = 0; j < 4; ++j)
        acc[i][j] = __builtin_amdgcn_mfma_f32_16x16x32_bf16(av[i], bv[j], acc[i][j], 0, 0, 0);
    __syncthreads();
  }

  const int orow = row0 + wr * 64 + (lane >> 4) * 4;
  const int ocol = col0 + wc * 64 + (lane & 15);
#pragma unroll
  for (int i = 0; i < 4; ++i)
#pragma unroll
    for (int j = 0; j < 4; ++j)
#pragma unroll
      for (int r = 0; r < 4; ++r)
        QKV[(size_t)(orow + i * 16 + r) * NQKV + ocol + j * 16] = f2bf(acc[i][j][r]);
}

// ---------------------------------------------------------------------------
// Causal flash attention, pair-balanced + double-buffered + swapped QK^T.
// Block = 4 waves; handles q-tile pair (p, 31-p): strip L rows p*64..,
// strip H rows (31-p)*64.. .  Both strips share staged K/V tiles.
// Swapped QK^T: St = mfma(K, Q) -> St[key][q], col=lane&15=q. Softmax is
// per-lane over 16 in-reg values + shfl_xor(16,32). P packed via
// v_cvt_pk_bf16_f32, 4x ds_write_b64, re-read as PV A-frags.
// ---------------------------------------------------------------------------
struct Strip {
  bf16x8 qf[2];
  f32x4  o[4];
  float  m, l;
};

__device__ __forceinline__ void strip_step(Strip& S, const char* cK, const char* cVt,
                                           char* cP, int l15, int lg, int kbase,
                                           int qcol, bool diag) {
  // ---- QK^T swapped: St[key][q] ----
  f32x4 st[4];
#pragma unroll
  for (int f = 0; f < 4; ++f)
#pragma unroll
    for (int r = 0; r < 4; ++r) st[f][r] = 0.f;

  __builtin_amdgcn_s_setprio(1);
#pragma unroll
  for (int c = 0; c < 2; ++c) {
#pragma unroll
    for (int f = 0; f < 4; ++f) {
      const int key = f * 16 + l15;
      const int off = (key * 128 + (c * 32 + lg * 8) * 2) ^ ((l15 & 7) << 4);
      bf16x8 kf = *(const bf16x8*)(cK + off);
      st[f] = __builtin_amdgcn_mfma_f32_16x16x32_bf16(kf, S.qf[c], st[f], 0, 0, 0);
    }
  }
  __builtin_amdgcn_s_setprio(0);

  if (diag) {
#pragma unroll
    for (int f = 0; f < 4; ++f) {
#pragma unroll
      for (int r = 0; r < 4; ++r) {
        const int kg = kbase + f * 16 + lg * 4 + r;
        if (kg > qcol) st[f][r] = -1e30f;
      }
    }
  }

  // ---- softmax (per-lane row q = qcol) ----
  float mx = st[0][0];
#pragma unroll
  for (int f = 0; f < 4; ++f)
#pragma unroll
    for (int r = 0; r < 4; ++r) mx = fmaxf(mx, st[f][r]);
  mx = fmaxf(mx, __shfl_xor(mx, 16));
  mx = fmaxf(mx, __shfl_xor(mx, 32));
  const float mnew = fmaxf(S.m, mx);
  const float corr = exp2f(S.m - mnew);
  S.m = mnew;

  float p[4][4];
  float ps = 0.f;
#pragma unroll
  for (int f = 0; f < 4; ++f)
#pragma unroll
    for (int r = 0; r < 4; ++r) {
      p[f][r] = exp2f(st[f][r] - mnew);
      ps += p[f][r];
    }
  ps += __shfl_xor(ps, 16);
  ps += __shfl_xor(ps, 32);
  S.l = S.l * corr + ps;

  // ---- rescale O (rows q = lg*4+r need corr from lane lg*4+r) ----
#pragma unroll
  for (int r = 0; r < 4; ++r) {
    const float cr = __shfl(corr, lg * 4 + r);
#pragma unroll
    for (int db = 0; db < 4; ++db) S.o[db][r] *= cr;
  }

  // ---- P -> LDS: rows q=l15, keys f*16+lg*4..+3 packed b64 ----
#pragma unroll
  for (int f = 0; f < 4; ++f) {
    uint2 w;
    w.x = cvt_pk_bf16(p[f][0], p[f][1]);
    w.y = cvt_pk_bf16(p[f][2], p[f][3]);
    *(uint2*)(cP + ((l15 * 128 + (f * 16 + lg * 4) * 2) ^ ((l15 & 7) << 4))) = w;
  }

  // ---- PV: O[q][dim] += P[q][key] * V[key][dim] ----
  __builtin_amdgcn_s_setprio(1);
#pragma unroll
  for (int c = 0; c < 2; ++c) {
    bf16x8 pa = *(const bf16x8*)(cP + ((l15 * 128 + (c * 32 + lg * 8) * 2) ^ ((l15 & 7) << 4)));
#pragma unroll
    for (int db = 0; db < 4; ++db) {
      const int dim = db * 16 + l15;
      const int boff = (dim * 128 + (c * 32 + lg * 8) * 2) ^ ((l15 & 7) << 4);
      bf16x8 vb = *(const bf16x8*)(cVt + boff);
      S.o[db] = __builtin_amdgcn_mfma_f32_16x16x32_bf16(pa, vb, S.o[db], 0, 0, 0);
    }
  }
  __builtin_amdgcn_s_setprio(0);
}

__global__ __launch_bounds__(256) void attn2(const unsigned short* __restrict__ QKV,
                                             float* __restrict__ Out) {
  __shared__ unsigned short sK [2][64 * 64];   // 16 KB
  __shared__ unsigned short sVt[2][64 * 64];   // 16 KB
  __shared__ unsigned short sP [4][16 * 64];   //  8 KB

  const int tid  = threadIdx.x;
  const int lane = tid & 63;
  const int wave = tid >> 6;
  const int l15  = lane & 15;
  const int lg   = lane >> 4;
  const int pidx = blockIdx.x;          // pair 0..15
  const int bh = blockIdx.y;
  const int b = bh >> 4, h = bh & 15;

  const int qtl = pidx, qth = 31 - pidx;
  const int q0l = qtl * 64, q0h = qth * 64;
  const int nstage = qth + 1;

  const unsigned short* Qbase = QKV + (size_t)(b * TOKENS) * NQKV + h * HDIM;
  const unsigned short* Kbase = Qbase + D_MODEL;
  const unsigned short* Vbase = Kbase + D_MODEL;

  // ---- load Q fragments for both strips (pre-scaled 0.125*log2e) ----
  Strip SL, SH;
#pragma unroll
  for (int db = 0; db < 4; ++db)
#pragma unroll
    for (int r = 0; r < 4; ++r) { SL.o[db][r] = 0.f; SH.o[db][r] = 0.f; }
  SL.m = -1e30f; SL.l = 0.f; SH.m = -1e30f; SH.l = 0.f;
  {
    union { unsigned short s[8]; bf16x8 v; ushort4 u[2]; } tmp;
#pragma unroll
    for (int c = 0; c < 2; ++c) {
      const unsigned short* pl = Qbase + (size_t)(q0l + wave * 16 + l15) * NQKV + c * 32 + lg * 8;
      tmp.u[0] = ((const ushort4*)pl)[0]; tmp.u[1] = ((const ushort4*)pl)[1];
#pragma unroll
      for (int e = 0; e < 8; ++e) tmp.s[e] = f2bf(bf2f(tmp.s[e]) * 0.18033688011112042f);
      SL.qf[c] = tmp.v;
      const unsigned short* ph = Qbase + (size_t)(q0h + wave * 16 + l15) * NQKV + c * 32 + lg * 8;
      tmp.u[0] = ((const ushort4*)ph)[0]; tmp.u[1] = ((const ushort4*)ph)[1];
#pragma unroll
      for (int e = 0; e < 8; ++e) tmp.s[e] = f2bf(bf2f(tmp.s[e]) * 0.18033688011112042f);
      SH.qf[c] = tmp.v;
    }
  }
  const int qcolL = q0l + wave * 16 + l15;
  const int qcolH = q0h + wave * 16 + l15;

  // ---- staging maps ----
  const int skey = tid >> 2;            // K row 0..63
  const int sd0  = (tid & 3) * 16;      // K dim start (elements)
  const int vk0  = (tid & 15) * 4;      // V key start
  const int vd0  = (tid >> 4) * 4;      // V dim start

  uint4 ka, kb2;
  ushort4 v0, v1, v2, v3;

#define LOAD_KV(kt)                                                            \
  {                                                                            \
    const unsigned short* ks = Kbase + (size_t)((kt) * 64 + skey) * NQKV + sd0;\
    ka  = ((const uint4*)ks)[0];                                               \
    kb2 = ((const uint4*)ks)[1];                                               \
    const unsigned short* vs = Vbase + (size_t)((kt) * 64 + vk0) * NQKV + vd0; \
    v0 = *(const ushort4*)(vs);                                                \
    v1 = *(const ushort4*)(vs + NQKV);                                         \
    v2 = *(const ushort4*)(vs + 2 * NQKV);                                     \
    v3 = *(const ushort4*)(vs + 3 * NQKV);                                     \
  }

#define WRITE_KV(buf)                                                          \
  {                                                                            \
    char* dK = (char*)&sK[(buf)][0];                                           \
    const int off = skey * 128 + sd0 * 2;                                      \
    const int sw  = (skey & 7) << 4;                                           \
    *(uint4*)(dK + ((off) ^ sw))      = ka;                                    \
    *(uint4*)(dK + ((off + 16) ^ sw)) = kb2;                                   \
    ushort4 c0, c1, c2, c3;                                                    \
    c0.x = v0.x; c0.y = v1.x; c0.z = v2.x; c0.w = v3.x;                        \
    c1.x = v0.y; c1.y = v1.y; c1.z = v2.y; c1.w = v3.y;                        \
    c2.x = v0.z; c2.y = v1.z; c2.z = v2.z; c2.w = v3.z;                        \
    c3.x = v0.w; c3.y = v1.w; c3.z = v2.w; c3.w = v3.w;                        \
    char* dV = (char*)&sVt[(buf)][0];                                          \
    _Pragma("unroll")                                                          \
    for (int e = 0; e < 4; ++e) {                                              \
      const int dim = vd0 + e;                                                 \
      const int o2 = (dim * 128 + vk0 * 2) ^ ((dim & 7) << 4);                 \
      ushort4 cc = (e == 0) ? c0 : (e == 1) ? c1 : (e == 2) ? c2 : c3;         \
      *(ushort4*)(dV + o2) = cc;                                               \
    }                                                                          \
  }

  LOAD_KV(0);
  WRITE_KV(0);
  __syncthreads();

  char* const cP = (char*)&sP[wave][0];

#pragma unroll 1
  for (int kt = 0; kt < nstage; ++kt) {
    const int cur = kt & 1;
    if (kt + 1 < nstage) LOAD_KV(kt + 1);

    const char* cK  = (const char*)&sK[cur][0];
    const char* cVt = (const char*)&sVt[cur][0];
    const int kbase = kt * 64;

    strip_step(SH, cK, cVt, cP, l15, lg, kbase, qcolH, kt == qth);
    if (kt <= qtl)
      strip_step(SL, cK, cVt, cP, l15, lg, kbase, qcolL, kt == qtl);

    if (kt + 1 < nstage) WRITE_KV((kt + 1) & 1);
    __syncthreads();
  }

  // ---- epilogue ----
  {
    const float invH = 1.f / SH.l;
    const float invL = 1.f / SL.l;
#pragma unroll
    for (int r = 0; r < 4; ++r) {
      const float ih = __shfl(invH, lg * 4 + r);
      const float il = __shfl(invL, lg * 4 + r);
      const int qh = q0h + wave * 16 + lg * 4 + r;
      const int ql = q0l + wave * 16 + lg * 4 + r;
      float* oh = Out + (size_t)(b * TOKENS + qh) * D_MODEL + h * HDIM;
      float* ol = Out + (size_t)(b * TOKENS + ql) * D_MODEL + h * HDIM;
#pragma unroll
      for (int db = 0; db < 4; ++db) {
        oh[db * 16 + l15] = SH.o[db][r] * ih;
        ol[db * 16 + l15] = SL.o[db][r] * il;
      }
    }
  }
}

extern "C" void kernel_launch(void* const* d_in, const int* in_sizes, int n_in,
                              void* d_out, int out_size, void* d_ws, size_t ws_size,
                              hipStream_t stream) {
  const float* X = (const float*)d_in[0];
  const float* W = (const float*)d_in[1];
  float* Out = (float*)d_out;
  unsigned short* QKV = (unsigned short*)d_ws;   // [4096][3072] bf16

  const size_t QKV_ELEMS = (size_t)MROWS * NQKV;           // 12.58M
  const size_t XB_ELEMS  = (size_t)MROWS * D_MODEL;        // 4.19M
  const size_t WB_ELEMS  = (size_t)NQKV * D_MODEL;         // 3.15M
  const size_t need = (QKV_ELEMS + XB_ELEMS + WB_ELEMS) * 2;

  if (ws_size >= need) {
    unsigned short* Xb = QKV + QKV_ELEMS;
    unsigned short* Wb = Xb + XB_ELEMS;
    cvt_bf16<<<(XB_ELEMS + WB_ELEMS) / (256 * 8), 256, 0, stream>>>(X, W, Xb, Wb);
    gemm_bf16<<<dim3(MROWS / 128, NQKV / 128), 256, 0, stream>>>(Xb, Wb, QKV);
  } else {
    qkv_gemm<<<dim3(MROWS / 128, NQKV / 128), 256, 0, stream>>>(X, W, QKV);
  }

  attn2<<<dim3(16, 2 * HEADS), 256, 0, stream>>>(QKV, Out);
}

// Round 5
// 126.164 us; speedup vs baseline: 9.6425x; 1.0163x over previous
//
#include <hip/hip_runtime.h>
#include <hip/hip_bf16.h>
#include <stdint.h>

#define D_MODEL 1024
#define TOKENS  2048
#define HEADS   16
#define HDIM    64
#define NQKV    3072      // 3*D_MODEL
#define MROWS   4096      // BATCH*TOKENS

typedef __attribute__((ext_vector_type(4))) float f32x4;
typedef __attribute__((ext_vector_type(8))) short bf16x8;

__device__ __forceinline__ unsigned short f2bf(float f) {
  union { float f; unsigned u; } v; v.f = f;
  unsigned u = v.u + 0x7FFFu + ((v.u >> 16) & 1u);   // RNE
  return (unsigned short)(u >> 16);
}
__device__ __forceinline__ float bf2f(unsigned short b) {
  union { unsigned u; float f; } v; v.u = ((unsigned)b) << 16;
  return v.f;
}
__device__ __forceinline__ unsigned cvt_pk_bf16(float lo, float hi) {
  unsigned r;
  asm("v_cvt_pk_bf16_f32 %0, %1, %2" : "=v"(r) : "v"(lo), "v"(hi));
  return r;
}

#define GLOAD16(g, l)                                                          \
  __builtin_amdgcn_global_load_lds(                                            \
      (const __attribute__((address_space(1))) unsigned int*)(g),              \
      (__attribute__((address_space(3))) unsigned int*)(l), 16, 0, 0)

// ---------------------------------------------------------------------------
// fp32 -> bf16 convert pass (X then W, contiguous).
// ---------------------------------------------------------------------------
__global__ __launch_bounds__(256) void cvt_bf16(const float* __restrict__ X,
                                                const float* __restrict__ W,
                                                unsigned short* __restrict__ Xb,
                                                unsigned short* __restrict__ Wb) {
  const size_t NX = (size_t)MROWS * D_MODEL;
  size_t i = ((size_t)blockIdx.x * 256 + threadIdx.x) * 8;
  const float* src; unsigned short* dst; size_t off;
  if (i < NX) { src = X; dst = Xb; off = i; }
  else        { src = W; dst = Wb; off = i - NX; }
  float4 a = ((const float4*)(src + off))[0];
  float4 b = ((const float4*)(src + off))[1];
  union { unsigned short s[8]; uint4 v; } u;
  u.s[0] = f2bf(a.x); u.s[1] = f2bf(a.y); u.s[2] = f2bf(a.z); u.s[3] = f2bf(a.w);
  u.s[4] = f2bf(b.x); u.s[5] = f2bf(b.y); u.s[6] = f2bf(b.z); u.s[7] = f2bf(b.w);
  *(uint4*)(dst + off) = u.v;
}

// ---------------------------------------------------------------------------
// bf16 GEMM (m97 structure): 128x128 tile, BK=64, global_load_lds width=16.
// ---------------------------------------------------------------------------
__global__ __launch_bounds__(256) void gemm_bf16(const unsigned short* __restrict__ A,
                                                 const unsigned short* __restrict__ B,
                                                 unsigned short* __restrict__ C) {
  __shared__ unsigned short sA[128 * 64];
  __shared__ unsigned short sB[128 * 64];
  const int tid  = threadIdx.x;
  const int lane = tid & 63;
  const int wave = tid >> 6;
  const int wr = wave >> 1, wc = wave & 1;
  const int row0 = blockIdx.x * 128;
  const int col0 = blockIdx.y * 128;

  f32x4 acc[4][4];
#pragma unroll
  for (int i = 0; i < 4; ++i)
#pragma unroll
    for (int j = 0; j < 4; ++j)
#pragma unroll
      for (int r = 0; r < 4; ++r) acc[i][j][r] = 0.f;

  const int lrow = lane & 15;
  const int lg   = lane >> 4;
  const int strow = (lane >> 3);
  const int stcol = (lane & 7) * 8;

#pragma unroll 1
  for (int k0 = 0; k0 < D_MODEL; k0 += 64) {
#pragma unroll
    for (int i = 0; i < 4; ++i) {
      const int r = wave * 32 + i * 8 + strow;
      GLOAD16(A + (size_t)(row0 + r) * D_MODEL + k0 + stcol, &sA[r * 64 + stcol]);
      GLOAD16(B + (size_t)(col0 + r) * D_MODEL + k0 + stcol, &sB[r * 64 + stcol]);
    }
    __syncthreads();

    bf16x8 av[4][2], bv[4][2];
#pragma unroll
    for (int c = 0; c < 2; ++c) {
#pragma unroll
      for (int i = 0; i < 4; ++i)
        av[i][c] = *(const bf16x8*)&sA[(wr * 64 + i * 16 + lrow) * 64 + c * 32 + lg * 8];
#pragma unroll
      for (int j = 0; j < 4; ++j)
        bv[j][c] = *(const bf16x8*)&sB[(wc * 64 + j * 16 + lrow) * 64 + c * 32 + lg * 8];
    }
#pragma unroll
    for (int c = 0; c < 2; ++c)
#pragma unroll
      for (int i = 0; i < 4; ++i)
#pragma unroll
        for (int j = 0; j < 4; ++j)
          acc[i][j] = __builtin_amdgcn_mfma_f32_16x16x32_bf16(av[i][c], bv[j][c], acc[i][j], 0, 0, 0);
    __syncthreads();
  }

  const int orow = row0 + wr * 64 + (lane >> 4) * 4;
  const int ocol = col0 + wc * 64 + (lane & 15);
#pragma unroll
  for (int i = 0; i < 4; ++i)
#pragma unroll
    for (int j = 0; j < 4; ++j)
#pragma unroll
      for (int r = 0; r < 4; ++r)
        C[(size_t)(orow + i * 16 + r) * NQKV + ocol + j * 16] = f2bf(acc[i][j][r]);
}

// ---------------------------------------------------------------------------
// Fallback fp32-input GEMM for small ws.
// ---------------------------------------------------------------------------
__global__ __launch_bounds__(256) void qkv_gemm(const float* __restrict__ X,
                                                const float* __restrict__ W,
                                                unsigned short* __restrict__ QKV) {
  __shared__ unsigned short sA[128 * 32];
  __shared__ unsigned short sB[128 * 32];
  const int tid  = threadIdx.x;
  const int lane = tid & 63;
  const int wave = tid >> 6;
  const int wr = wave >> 1, wc = wave & 1;
  const int row0 = blockIdx.x * 128;
  const int col0 = blockIdx.y * 128;

  f32x4 acc[4][4];
#pragma unroll
  for (int i = 0; i < 4; ++i)
#pragma unroll
    for (int j = 0; j < 4; ++j)
#pragma unroll
      for (int r = 0; r < 4; ++r) acc[i][j][r] = 0.f;

  const int srow = tid >> 1;
  const int scol = (tid & 1) * 16;
  union U16 { unsigned short s[8]; uint4 v; };

#pragma unroll 1
  for (int k0 = 0; k0 < D_MODEL; k0 += 32) {
    {
      const float* ga = X + (size_t)(row0 + srow) * D_MODEL + k0 + scol;
      const float* gb = W + (size_t)(col0 + srow) * D_MODEL + k0 + scol;
      float va[16], vb[16];
#pragma unroll
      for (int i = 0; i < 4; ++i) {
        float4 t = ((const float4*)ga)[i];
        va[4*i+0] = t.x; va[4*i+1] = t.y; va[4*i+2] = t.z; va[4*i+3] = t.w;
        float4 u = ((const float4*)gb)[i];
        vb[4*i+0] = u.x; vb[4*i+1] = u.y; vb[4*i+2] = u.z; vb[4*i+3] = u.w;
      }
      U16 ua0, ua1, ub0, ub1;
#pragma unroll
      for (int e = 0; e < 8; ++e) {
        ua0.s[e] = f2bf(va[e]);   ua1.s[e] = f2bf(va[8 + e]);
        ub0.s[e] = f2bf(vb[e]);   ub1.s[e] = f2bf(vb[8 + e]);
      }
      *(uint4*)&sA[srow * 32 + scol + 0] = ua0.v;
      *(uint4*)&sA[srow * 32 + scol + 8] = ua1.v;
      *(uint4*)&sB[srow * 32 + scol + 0] = ub0.v;
      *(uint4*)&sB[srow * 32 + scol + 8] = ub1.v;
    }
    __syncthreads();

    const int lrow = lane & 15;
    const int lk   = (lane >> 4) * 8;
    bf16x8 av[4], bv[4];
#pragma unroll
    for (int i = 0; i < 4; ++i)
      av[i] = *(const bf16x8*)&sA[(wr * 64 + i * 16 + lrow) * 32 + lk];
#pragma unroll
    for (int j = 0; j < 4; ++j)
      bv[j] = *(const bf16x8*)&sB[(wc * 64 + j * 16 + lrow) * 32 + lk];
#pragma unroll
    for (int i = 0; i < 4; ++i)
#pragma unroll
      for (int j = 0; j < 4; ++j)
        acc[i][j] = __builtin_amdgcn_mfma_f32_16x16x32_bf16(av[i], bv[j], acc[i][j], 0, 0, 0);
    __syncthreads();
  }

  const int orow = row0 + wr * 64 + (lane >> 4) * 4;
  const int ocol = col0 + wc * 64 + (lane & 15);
#pragma unroll
  for (int i = 0; i < 4; ++i)
#pragma unroll
    for (int j = 0; j < 4; ++j)
#pragma unroll
      for (int r = 0; r < 4; ++r)
        QKV[(size_t)(orow + i * 16 + r) * NQKV + ocol + j * 16] = f2bf(acc[i][j][r]);
}

// ---------------------------------------------------------------------------
// Causal flash attention v3: pair-balanced + double-buffered + swapped QK^T
// + swapped PV (O in [dim][q] form -> lane-local m/l/corr, no shfl broadcasts)
// + defer-rescale (THR=8 in exp2 domain).
// ---------------------------------------------------------------------------
struct Strip {
  bf16x8 qf[2];
  f32x4  o[4];    // o[db][r] = O[dim = db*16 + lg*4 + r][q = l15]
  float  m, l;    // per-lane (q = l15), identical across lg groups
};

__device__ __forceinline__ void strip_step(Strip& S, const char* cK, const char* cVt,
                                           char* cP, int l15, int lg, int kbase,
                                           int qcol, bool diag) {
  // ---- QK^T swapped: St[key][q], key = f*16+lg*4+r, q = l15 ----
  f32x4 st[4];
#pragma unroll
  for (int f = 0; f < 4; ++f)
#pragma unroll
    for (int r = 0; r < 4; ++r) st[f][r] = 0.f;

  __builtin_amdgcn_s_setprio(1);
#pragma unroll
  for (int c = 0; c < 2; ++c) {
#pragma unroll
    for (int f = 0; f < 4; ++f) {
      const int key = f * 16 + l15;
      const int off = (key * 128 + (c * 32 + lg * 8) * 2) ^ ((l15 & 7) << 4);
      bf16x8 kf = *(const bf16x8*)(cK + off);
      st[f] = __builtin_amdgcn_mfma_f32_16x16x32_bf16(kf, S.qf[c], st[f], 0, 0, 0);
    }
  }
  __builtin_amdgcn_s_setprio(0);

  if (diag) {
#pragma unroll
    for (int f = 0; f < 4; ++f) {
#pragma unroll
      for (int r = 0; r < 4; ++r) {
        const int kg = kbase + f * 16 + lg * 4 + r;
        if (kg > qcol) st[f][r] = -1e30f;
      }
    }
  }

  // ---- pairwise max tree (per-lane 16 -> cross-group shfl 16/32) ----
  float a0 = fmaxf(st[0][0], st[0][1]), a1 = fmaxf(st[0][2], st[0][3]);
  float a2 = fmaxf(st[1][0], st[1][1]), a3 = fmaxf(st[1][2], st[1][3]);
  float a4 = fmaxf(st[2][0], st[2][1]), a5 = fmaxf(st[2][2], st[2][3]);
  float a6 = fmaxf(st[3][0], st[3][1]), a7 = fmaxf(st[3][2], st[3][3]);
  float b0 = fmaxf(a0, a1), b1 = fmaxf(a2, a3), b2 = fmaxf(a4, a5), b3 = fmaxf(a6, a7);
  float mx = fmaxf(fmaxf(b0, b1), fmaxf(b2, b3));
  mx = fmaxf(mx, __shfl_xor(mx, 16));
  mx = fmaxf(mx, __shfl_xor(mx, 32));

  // ---- defer-rescale: only rescale when max grew by > 8 (exp2 domain) ----
  if (!__all(mx - S.m <= 8.f)) {
    const float mnew = fmaxf(S.m, mx);
    const float corr = exp2f(S.m - mnew);
    S.m = mnew;
    S.l *= corr;
#pragma unroll
    for (int db = 0; db < 4; ++db)
#pragma unroll
      for (int r = 0; r < 4; ++r) S.o[db][r] *= corr;
  }

  // ---- P = exp2(st - m), sum tree ----
  float p[4][4];
#pragma unroll
  for (int f = 0; f < 4; ++f)
#pragma unroll
    for (int r = 0; r < 4; ++r) p[f][r] = exp2f(st[f][r] - S.m);
  float s0 = (p[0][0] + p[0][1]) + (p[0][2] + p[0][3]);
  float s1 = (p[1][0] + p[1][1]) + (p[1][2] + p[1][3]);
  float s2 = (p[2][0] + p[2][1]) + (p[2][2] + p[2][3]);
  float s3 = (p[3][0] + p[3][1]) + (p[3][2] + p[3][3]);
  float ps = (s0 + s1) + (s2 + s3);
  ps += __shfl_xor(ps, 16);
  ps += __shfl_xor(ps, 32);
  S.l += ps;

  // ---- P -> LDS: row q=l15, keys f*16+lg*4..+3, packed b64 ----
#pragma unroll
  for (int f = 0; f < 4; ++f) {
    uint2 w;
    w.x = cvt_pk_bf16(p[f][0], p[f][1]);
    w.y = cvt_pk_bf16(p[f][2], p[f][3]);
    *(uint2*)(cP + ((l15 * 128 + (f * 16 + lg * 4) * 2) ^ ((l15 & 7) << 4))) = w;
  }

  // ---- PV swapped: O[dim][q] += (P V)^T -> mfma(V, P) ----
  __builtin_amdgcn_s_setprio(1);
#pragma unroll
  for (int c = 0; c < 2; ++c) {
    bf16x8 pa = *(const bf16x8*)(cP + ((l15 * 128 + (c * 32 + lg * 8) * 2) ^ ((l15 & 7) << 4)));
#pragma unroll
    for (int db = 0; db < 4; ++db) {
      const int dim = db * 16 + l15;
      const int boff = (dim * 128 + (c * 32 + lg * 8) * 2) ^ ((l15 & 7) << 4);
      bf16x8 vb = *(const bf16x8*)(cVt + boff);
      S.o[db] = __builtin_amdgcn_mfma_f32_16x16x32_bf16(vb, pa, S.o[db], 0, 0, 0);
    }
  }
  __builtin_amdgcn_s_setprio(0);
}

__global__ __launch_bounds__(256) void attn3(const unsigned short* __restrict__ QKV,
                                             float* __restrict__ Out) {
  __shared__ unsigned short sK [2][64 * 64];
  __shared__ unsigned short sVt[2][64 * 64];
  __shared__ unsigned short sP [4][16 * 64];

  const int tid  = threadIdx.x;
  const int lane = tid & 63;
  const int wave = tid >> 6;
  const int l15  = lane & 15;
  const int lg   = lane >> 4;
  const int pidx = blockIdx.x;
  const int bh = blockIdx.y;
  const int b = bh >> 4, h = bh & 15;

  const int qtl = pidx, qth = 31 - pidx;
  const int q0l = qtl * 64, q0h = qth * 64;
  const int nstage = qth + 1;

  const unsigned short* Qbase = QKV + (size_t)(b * TOKENS) * NQKV + h * HDIM;
  const unsigned short* Kbase = Qbase + D_MODEL;
  const unsigned short* Vbase = Kbase + D_MODEL;

  Strip SL, SH;
#pragma unroll
  for (int db = 0; db < 4; ++db)
#pragma unroll
    for (int r = 0; r < 4; ++r) { SL.o[db][r] = 0.f; SH.o[db][r] = 0.f; }
  SL.m = -1e30f; SL.l = 0.f; SH.m = -1e30f; SH.l = 0.f;
  {
    union { unsigned short s[8]; bf16x8 v; ushort4 u[2]; } tmp;
#pragma unroll
    for (int c = 0; c < 2; ++c) {
      const unsigned short* pl = Qbase + (size_t)(q0l + wave * 16 + l15) * NQKV + c * 32 + lg * 8;
      tmp.u[0] = ((const ushort4*)pl)[0]; tmp.u[1] = ((const ushort4*)pl)[1];
#pragma unroll
      for (int e = 0; e < 8; ++e) tmp.s[e] = f2bf(bf2f(tmp.s[e]) * 0.18033688011112042f);
      SL.qf[c] = tmp.v;
      const unsigned short* ph = Qbase + (size_t)(q0h + wave * 16 + l15) * NQKV + c * 32 + lg * 8;
      tmp.u[0] = ((const ushort4*)ph)[0]; tmp.u[1] = ((const ushort4*)ph)[1];
#pragma unroll
      for (int e = 0; e < 8; ++e) tmp.s[e] = f2bf(bf2f(tmp.s[e]) * 0.18033688011112042f);
      SH.qf[c] = tmp.v;
    }
  }
  const int qcolL = q0l + wave * 16 + l15;
  const int qcolH = q0h + wave * 16 + l15;

  const int skey = tid >> 2;
  const int sd0  = (tid & 3) * 16;
  const int vk0  = (tid & 15) * 4;
  const int vd0  = (tid >> 4) * 4;

  uint4 ka, kb2;
  ushort4 v0, v1, v2, v3;

#define LOAD_KV(kt)                                                            \
  {                                                                            \
    const unsigned short* ks = Kbase + (size_t)((kt) * 64 + skey) * NQKV + sd0;\
    ka  = ((const uint4*)ks)[0];                                               \
    kb2 = ((const uint4*)ks)[1];                                               \
    const unsigned short* vs = Vbase + (size_t)((kt) * 64 + vk0) * NQKV + vd0; \
    v0 = *(const ushort4*)(vs);                                                \
    v1 = *(const ushort4*)(vs + NQKV);                                         \
    v2 = *(const ushort4*)(vs + 2 * NQKV);                                     \
    v3 = *(const ushort4*)(vs + 3 * NQKV);                                     \
  }

#define WRITE_KV(buf)                                                          \
  {                                                                            \
    char* dK = (char*)&sK[(buf)][0];                                           \
    const int off = skey * 128 + sd0 * 2;                                      \
    const int sw  = (skey & 7) << 4;                                           \
    *(uint4*)(dK + ((off) ^ sw))      = ka;                                    \
    *(uint4*)(dK + ((off + 16) ^ sw)) = kb2;                                   \
    ushort4 c0, c1, c2, c3;                                                    \
    c0.x = v0.x; c0.y = v1.x; c0.z = v2.x; c0.w = v3.x;                        \
    c1.x = v0.y; c1.y = v1.y; c1.z = v2.y; c1.w = v3.y;                        \
    c2.x = v0.z; c2.y = v1.z; c2.z = v2.z; c2.w = v3.z;                        \
    c3.x = v0.w; c3.y = v1.w; c3.z = v2.w; c3.w = v3.w;                        \
    char* dV = (char*)&sVt[(buf)][0];                                          \
    _Pragma("unroll")                                                          \
    for (int e = 0; e < 4; ++e) {                                              \
      const int dim = vd0 + e;                                                 \
      const int o2 = (dim * 128 + vk0 * 2) ^ ((dim & 7) << 4);                 \
      ushort4 cc = (e == 0) ? c0 : (e == 1) ? c1 : (e == 2) ? c2 : c3;         \
      *(ushort4*)(dV + o2) = cc;                                               \
    }                                                                          \
  }

  LOAD_KV(0);
  WRITE_KV(0);
  __syncthreads();

  char* const cP = (char*)&sP[wave][0];

#pragma unroll 1
  for (int kt = 0; kt < nstage; ++kt) {
    const int cur = kt & 1;
    if (kt + 1 < nstage) LOAD_KV(kt + 1);

    const char* cK  = (const char*)&sK[cur][0];
    const char* cVt = (const char*)&sVt[cur][0];
    const int kbase = kt * 64;

    strip_step(SH, cK, cVt, cP, l15, lg, kbase, qcolH, kt == qth);
    if (kt <= qtl)
      strip_step(SL, cK, cVt, cP, l15, lg, kbase, qcolL, kt == qtl);

    if (kt + 1 < nstage) WRITE_KV((kt + 1) & 1);
    __syncthreads();
  }

  // ---- epilogue: lane-local normalize, scattered stores ----
  {
    const float ih = 1.f / SH.l;
    const float il = 1.f / SL.l;
    const int qh = q0h + wave * 16 + l15;
    const int ql = q0l + wave * 16 + l15;
    float* oh = Out + (size_t)(b * TOKENS + qh) * D_MODEL + h * HDIM;
    float* ol = Out + (size_t)(b * TOKENS + ql) * D_MODEL + h * HDIM;
#pragma unroll
    for (int db = 0; db < 4; ++db)
#pragma unroll
      for (int r = 0; r < 4; ++r) {
        oh[db * 16 + lg * 4 + r] = SH.o[db][r] * ih;
        ol[db * 16 + lg * 4 + r] = SL.o[db][r] * il;
      }
  }
}

extern "C" void kernel_launch(void* const* d_in, const int* in_sizes, int n_in,
                              void* d_out, int out_size, void* d_ws, size_t ws_size,
                              hipStream_t stream) {
  const float* X = (const float*)d_in[0];
  const float* W = (const float*)d_in[1];
  float* Out = (float*)d_out;
  unsigned short* QKV = (unsigned short*)d_ws;

  const size_t QKV_ELEMS = (size_t)MROWS * NQKV;
  const size_t XB_ELEMS  = (size_t)MROWS * D_MODEL;
  const size_t WB_ELEMS  = (size_t)NQKV * D_MODEL;
  const size_t need = (QKV_ELEMS + XB_ELEMS + WB_ELEMS) * 2;

  if (ws_size >= need) {
    unsigned short* Xb = QKV + QKV_ELEMS;
    unsigned short* Wb = Xb + XB_ELEMS;
    cvt_bf16<<<(XB_ELEMS + WB_ELEMS) / (256 * 8), 256, 0, stream>>>(X, W, Xb, Wb);
    gemm_bf16<<<dim3(MROWS / 128, NQKV / 128), 256, 0, stream>>>(Xb, Wb, QKV);
  } else {
    qkv_gemm<<<dim3(MROWS / 128, NQKV / 128), 256, 0, stream>>>(X, W, QKV);
  }

  attn3<<<dim3(16, 2 * HEADS), 256, 0, stream>>>(QKV, Out);
}